// Round 11
// baseline (844.989 us; speedup 1.0000x reference)
//
#include <hip/hip_runtime.h>
#include <math.h>

#define D      128
#define S_LEN  64
#define B_SZ   512
#define NH     4
#define DH     32
#define NB     2
#define VOCAB  9
#define EPS    1e-5f
#define NTOK   (B_SZ * S_LEN)

#define XS_STRIDE 132   // 128 + 4: rotates banks across token rows

// ---------------- DPP helpers (ctrl must be compile-time constant) ----------
template <int CTRL>
__device__ __forceinline__ float dppf(float x) {
    return __int_as_float(__builtin_amdgcn_update_dpp(
        0, __float_as_int(x), CTRL, 0xF, 0xF, true));
}
__device__ __forceinline__ float wsum64(float x) {
    x += dppf<0x111>(x);
    x += dppf<0x112>(x);
    x += dppf<0x114>(x);
    x += dppf<0x118>(x);
    x += dppf<0x142>(x);
    x += dppf<0x143>(x);
    return __int_as_float(__builtin_amdgcn_readlane(__float_as_int(x), 63));
}
// output-column swizzle for wt: spreads the 16 b128 read addrs over all banks
__device__ __forceinline__ int swz(int o) { return o ^ (((o >> 5) & 3) << 2); }
__device__ __forceinline__ int xg (int c) { return c ^ ((c >> 5) << 3); }

// ---------------------------------------------------------------------------
// Kernel 1: h = emb[x]; LN1 stats. One wave per token.
// ---------------------------------------------------------------------------
__global__ __launch_bounds__(256) void k_embed(const int* __restrict__ x,
                                               const float* __restrict__ emb,
                                               float* __restrict__ h,
                                               float* __restrict__ stats)
{
    int lane = threadIdx.x & 63;
    int wv   = threadIdx.x >> 6;
    int tok  = blockIdx.x * 4 + wv;
    int xi   = x[tok];
    float2 v = ((const float2*)(emb + xi * D))[lane];
    ((float2*)(h + (size_t)tok * D))[lane] = v;
    float s1 = wsum64(v.x + v.y);
    float s2 = wsum64(v.x * v.x + v.y * v.y);
    float mu  = s1 * (1.0f / D);
    float var = s2 * (1.0f / D) - mu * mu;
    if (lane == 0) {
        stats[tok * 2]     = mu;
        stats[tok * 2 + 1] = rsqrtf(var + EPS);
    }
}

// ---------------------------------------------------------------------------
// Kernel 1.5: gx = LN1(h) @ Wg + bias (unchanged from R10).
// ---------------------------------------------------------------------------
__global__ __launch_bounds__(256, 2) void k_gx(const float* __restrict__ Wg,
                                               const float* __restrict__ bias,
                                               const float* __restrict__ lnw,
                                               const float* __restrict__ h,
                                               const float* __restrict__ stats,
                                               float* __restrict__ gx)
{
    __shared__ float xs[32 * 128];
    __shared__ float wl[4 * 32 * 128];

    int tid  = threadIdx.x;
    int lane = tid & 63;
    int wv   = tid >> 6;
    size_t tok0 = (size_t)blockIdx.x * 32;

    {
        int q = tid & 7;
        #pragma unroll
        for (int it = 0; it < 16; ++it) {
            int row = it * 32 + (tid >> 3);
            int g  = row >> 7;
            int n  = (row >> 5) & 3;
            int hh = row & 31;
            float4 v = *(const float4*)(Wg + row * 32 + q * 4);
            int col = g * 32 + hh;
            int sw  = q << 2;
            float* dst = wl + n * 4096;
            dst[(q * 4 + 0) * 128 + (col ^ sw)] = v.x;
            dst[(q * 4 + 1) * 128 + (col ^ sw)] = v.y;
            dst[(q * 4 + 2) * 128 + (col ^ sw)] = v.z;
            dst[(q * 4 + 3) * 128 + (col ^ sw)] = v.w;
        }
    }
    for (int i = 0; i < 8; ++i) {
        int t = wv * 8 + i;
        const float* hp = h + (tok0 + t) * D;
        float mu = stats[(tok0 + t) * 2];
        float rs = stats[(tok0 + t) * 2 + 1];
        float v1 = (hp[lane]      - mu) * rs * lnw[lane];
        float v2 = (hp[64 + lane] - mu) * rs * lnw[64 + lane];
        xs[t * 128 + xg(lane)]      = v1;
        xs[t * 128 + xg(lane + 64)] = v2;
    }
    __syncthreads();

    int nh   = lane >> 4;
    int col0 = (lane & 15) * 8;
    int t0   = wv * 8;

    float acc[8][8];
    #pragma unroll
    for (int j = 0; j < 8; ++j)
        #pragma unroll
        for (int cc = 0; cc < 8; ++cc) acc[j][cc] = 0.f;

    const float* wbase = wl + nh * 4096;
    #pragma unroll
    for (int k4 = 0; k4 < 8; ++k4) {
        int sw  = k4 << 2;
        int ac4 = (nh * 32 + k4 * 4) ^ (nh << 3);
        float4 w0[4], w1[4];
        #pragma unroll
        for (int i = 0; i < 4; ++i) {
            int k = k4 * 4 + i;
            w0[i] = *(const float4*)&wbase[k * 128 + (col0 ^ sw)];
            w1[i] = *(const float4*)&wbase[k * 128 + ((col0 + 4) ^ sw)];
        }
        #pragma unroll
        for (int j = 0; j < 8; ++j) {
            float4 a4 = *(const float4*)&xs[(t0 + j) * 128 + ac4];
            #pragma unroll
            for (int i = 0; i < 4; ++i) {
                float a = ((const float*)&a4)[i];
                acc[j][0] = fmaf(a, w0[i].x, acc[j][0]);
                acc[j][1] = fmaf(a, w0[i].y, acc[j][1]);
                acc[j][2] = fmaf(a, w0[i].z, acc[j][2]);
                acc[j][3] = fmaf(a, w0[i].w, acc[j][3]);
                acc[j][4] = fmaf(a, w1[i].x, acc[j][4]);
                acc[j][5] = fmaf(a, w1[i].y, acc[j][5]);
                acc[j][6] = fmaf(a, w1[i].z, acc[j][6]);
                acc[j][7] = fmaf(a, w1[i].w, acc[j][7]);
            }
        }
    }

    float4 bb0 = *(const float4*)(bias + nh * 128 + col0);
    float4 bb1 = *(const float4*)(bias + nh * 128 + col0 + 4);
    #pragma unroll
    for (int j = 0; j < 8; ++j) {
        int gt = (int)tok0 + t0 + j;
        int bb = gt >> 6;
        int ss = gt & 63;
        float* op = gx + ((size_t)(bb * NH + nh) * S_LEN + ss) * 128 + col0;
        float4 o0v, o1v;
        o0v.x = acc[j][0] + bb0.x; o0v.y = acc[j][1] + bb0.y;
        o0v.z = acc[j][2] + bb0.z; o0v.w = acc[j][3] + bb0.w;
        o1v.x = acc[j][4] + bb1.x; o1v.y = acc[j][5] + bb1.y;
        o1v.z = acc[j][6] + bb1.z; o1v.w = acc[j][7] + bb1.w;
        *(float4*)op       = o0v;
        *(float4*)(op + 4) = o1v;
    }
}

// ---------------------------------------------------------------------------
// Kernel 2: sLSTM scan. R8's empty non-volatile asm was DELETED by LLVM
// (hence byte-identical counters R7/R8). asm volatile cannot be deleted or
// sunk into the loop -> the R loads become once-only opaque VGPR defs.
// (64,1): 512-VGPR budget, grid gives 2 waves/SIMD.
// ---------------------------------------------------------------------------
__global__ __launch_bounds__(64, 1) void k_scan(const float* __restrict__ Rm,
                                                const float* __restrict__ gnw,
                                                const float* __restrict__ gx,
                                                float* __restrict__ h)
{
    int b    = blockIdx.x >> 2;
    int n    = blockIdx.x & 3;
    int lane = threadIdx.x;
    int e    = lane >> 1;
    int sub  = lane & 1;
    int colA = sub * DH + e;           // i (sub0) / f (sub1); +64 -> z/o

    float RA[DH], RB[DH];
    #pragma unroll
    for (int i = 0; i < DH; ++i) {
        RA[i] = Rm[(n * DH + i) * 128 + colA];
        RB[i] = Rm[(n * DH + i) * 128 + 64 + colA];
    }
    // volatile: cannot be deleted (R8's non-volatile was) nor sunk into loop
    #pragma unroll
    for (int i = 0; i < DH; ++i) {
        asm volatile("" : "+v"(RA[i]));
        asm volatile("" : "+v"(RB[i]));
    }
    float gw = gnw[n * DH + e];

    float c = 0.f, nacc = 0.f, m = 0.f;
    float hu[DH];
    #pragma unroll
    for (int i = 0; i < DH; ++i) hu[i] = 0.f;

    float* hb = h + ((size_t)b * S_LEN) * D + n * DH;
    const float* gxp = gx + ((size_t)(b * NH + n) * S_LEN) * 128;

    float pGA[4], pGB[4], pHR[4];
    #pragma unroll
    for (int k = 0; k < 4; ++k) {
        pGA[k] = gxp[k * 128 + colA];
        pGB[k] = gxp[k * 128 + 64 + colA];
        pHR[k] = hb[k * D + e];
    }

    for (int s = 0; s < S_LEN; ++s) {
        int sp = (s + 4 < S_LEN) ? s + 4 : S_LEN - 1;
        float nGA = gxp[sp * 128 + colA];
        float nGB = gxp[sp * 128 + 64 + colA];
        float nHR = hb[sp * D + e];

        float r0=0,r1=0,r2=0,r3=0,q0=0,q1=0,q2=0,q3=0;
        #pragma unroll
        for (int i = 0; i < DH; i += 4) {
            r0 = fmaf(hu[i],   RA[i],   r0);
            r1 = fmaf(hu[i+1], RA[i+1], r1);
            r2 = fmaf(hu[i+2], RA[i+2], r2);
            r3 = fmaf(hu[i+3], RA[i+3], r3);
            q0 = fmaf(hu[i],   RB[i],   q0);
            q1 = fmaf(hu[i+1], RB[i+1], q1);
            q2 = fmaf(hu[i+2], RB[i+2], q2);
            q3 = fmaf(hu[i+3], RB[i+3], q3);
        }
        float rawA = pGA[0] + ((r0 + r1) + (r2 + r3));
        float rawB = pGB[0] + ((q0 + q1) + (q2 + q3));

        float xA = dppf<0xB1>(rawA);
        float xB = dppf<0xB1>(rawB);
        float i_r = sub ? xA   : rawA;
        float f_r = sub ? rawA : xA;
        float z_r = sub ? xB   : rawB;
        float o_r = sub ? rawB : xB;

        float lsf  = fminf(f_r, 0.f)
                   - 0.69314718055994531f * __log2f(1.0f + __expf(-fabsf(f_r)));
        float lfm  = m + lsf;
        float mnew = fmaxf(i_r, lfm);
        float ig   = __expf(i_r - mnew);
        float fg   = __expf(lfm - mnew);
        float t    = __expf(2.f * z_r);
        float tz   = 1.f - 2.f / (t + 1.f);
        c    = fg * c + ig * tz;
        nacc = fg * nacc + ig;
        m    = mnew;
        float hv = c / (nacc * (1.f + __expf(-o_r)));

        float s1 = wsum64(hv);
        float s2 = wsum64(hv * hv);
        float mu  = s1 * (1.f / 64.f);
        float var = s2 * (1.f / 64.f) - mu * mu;
        float hn  = (hv - mu) * rsqrtf(var + EPS) * gw;

        if (!sub) hb[s * D + e] = pHR[0] + hn;

        #pragma unroll
        for (int i = 0; i < DH; ++i)
            hu[i] = __int_as_float(
                __builtin_amdgcn_readlane(__float_as_int(hv), 2 * i));

        pGA[0]=pGA[1]; pGA[1]=pGA[2]; pGA[2]=pGA[3]; pGA[3]=nGA;
        pGB[0]=pGB[1]; pGB[1]=pGB[2]; pGB[2]=pGB[3]; pGB[3]=nGB;
        pHR[0]=pHR[1]; pHR[1]=pHR[2]; pHR[2]=pHR[3]; pHR[3]=nHR;
    }
}

// ---------------------------------------------------------------------------
// Kernel 3 (rewritten): 64 tokens/block, 256 threads, single full-width up
// pass (no p-loop). Thread tile: 4 tokens x 8 col-pairs (64 up acc).
// Per k4: 20 LDS reads for 256 FMA (old: 10 per 64). a-reads are 4-addr
// wave broadcasts; xs stride 132 + swz() on wt keep all accesses <=2-way.
// xs (33 KB) is reused for act after the up phase. 16 barriers (was 24).
// ---------------------------------------------------------------------------
template <int LAST>
__global__ __launch_bounds__(256, 1) void k_ff(float* __restrict__ h,
                                               const float* __restrict__ ln2w,
                                               const float* __restrict__ wup,    // (256, 128)
                                               const float* __restrict__ wdn,    // (128, 128)
                                               float* __restrict__ stats_out,
                                               const float* __restrict__ lastw,
                                               const float* __restrict__ projw,
                                               const float* __restrict__ projb,
                                               float* __restrict__ out)
{
    __shared__ float xs[64 * XS_STRIDE];   // 33 KiB: xn, then act, then hnew
    __shared__ float wt[32 * 256];         // 32 KiB: [k][out'] (swizzled cols)

    int tid  = threadIdx.x;
    int lane = tid & 63;
    int wv   = tid >> 6;
    size_t tok0 = (size_t)blockIdx.x * 64;

    int ti = tid >> 4;          // 0..15 -> tokens ti*4..+3
    int oi = tid & 15;          // 0..15 -> col pairs oi*8..+7 (and +128)
    int o0 = oi * 8;
    int og = swz(o0);           // og+4 == swz(o0+4); 128+og == swz(128+o0)
    int srow_u = swz(tid);              // up-store swizzled row
    int srow_d = swz(tid >> 1);         // down-store swizzled row

    float4 pre[8];
    auto ffld_up = [&](int c) {
        const float* p = wup + tid * 128 + c * 32;
        #pragma unroll
        for (int q = 0; q < 8; ++q) pre[q] = *(const float4*)(p + q * 4);
    };
    auto fst_up = [&]() {
        #pragma unroll
        for (int q = 0; q < 8; ++q)
            #pragma unroll
            for (int jj = 0; jj < 4; ++jj)
                wt[(q * 4 + jj) * 256 + srow_u] = ((const float*)&pre[q])[jj];
    };
    auto ffld_dn = [&](int c) {
        const float* p = wdn + (tid >> 1) * 128 + c * 32 + (tid & 1) * 16;
        #pragma unroll
        for (int q = 0; q < 4; ++q) pre[q] = *(const float4*)(p + q * 4);
    };
    auto fst_dn = [&]() {
        int kb = (tid & 1) * 16;
        #pragma unroll
        for (int q = 0; q < 4; ++q)
            #pragma unroll
            for (int jj = 0; jj < 4; ++jj)
                wt[(kb + q * 4 + jj) * 128 + srow_d] = ((const float*)&pre[q])[jj];
    };

    // ---- LN2 into xs (16 tokens per wave) + first up chunk staged ----
    ffld_up(0);
    for (int i = 0; i < 16; ++i) {
        int t = wv * 16 + i;
        const float* hp = h + (tok0 + t) * D;
        float v1 = hp[lane], v2 = hp[64 + lane];
        float s1 = wsum64(v1 + v2);
        float s2 = wsum64(v1 * v1 + v2 * v2);
        float mu = s1 * (1.0f / D);
        float rs = rsqrtf(s2 * (1.0f / D) - mu * mu + EPS);
        xs[t * XS_STRIDE + lane]      = (v1 - mu) * rs * ln2w[lane];
        xs[t * XS_STRIDE + 64 + lane] = (v2 - mu) * rs * ln2w[64 + lane];
    }
    fst_up();
    ffld_up(1);
    __syncthreads();

    float accg[4][8], accv[4][8];
    #pragma unroll
    for (int j = 0; j < 4; ++j)
        #pragma unroll
        for (int cc = 0; cc < 8; ++cc) { accg[j][cc] = 0.f; accv[j][cc] = 0.f; }

    // ---- UP: 4 chunks of 32 k ----
    for (int c = 0; c < 4; ++c) {
        const float* xsp = xs + (ti * 4) * XS_STRIDE + c * 32;
        #pragma unroll
        for (int k4 = 0; k4 < 8; ++k4) {
            float4 a[4];
            #pragma unroll
            for (int j = 0; j < 4; ++j)
                a[j] = *(const float4*)&xsp[j * XS_STRIDE + k4 * 4];
            #pragma unroll
            for (int i = 0; i < 4; ++i) {
                const float* wr = wt + (k4 * 4 + i) * 256;
                float4 g0 = *(const float4*)&wr[og];
                float4 g1 = *(const float4*)&wr[og + 4];
                float4 v0 = *(const float4*)&wr[128 + og];
                float4 v1 = *(const float4*)&wr[128 + og + 4];
                #pragma unroll
                for (int j = 0; j < 4; ++j) {
                    float av = ((const float*)&a[j])[i];
                    accg[j][0] = fmaf(av, g0.x, accg[j][0]);
                    accg[j][1] = fmaf(av, g0.y, accg[j][1]);
                    accg[j][2] = fmaf(av, g0.z, accg[j][2]);
                    accg[j][3] = fmaf(av, g0.w, accg[j][3]);
                    accg[j][4] = fmaf(av, g1.x, accg[j][4]);
                    accg[j][5] = fmaf(av, g1.y, accg[j][5]);
                    accg[j][6] = fmaf(av, g1.z, accg[j][6]);
                    accg[j][7] = fmaf(av, g1.w, accg[j][7]);
                    accv[j][0] = fmaf(av, v0.x, accv[j][0]);
                    accv[j][1] = fmaf(av, v0.y, accv[j][1]);
                    accv[j][2] = fmaf(av, v0.z, accv[j][2]);
                    accv[j][3] = fmaf(av, v0.w, accv[j][3]);
                    accv[j][4] = fmaf(av, v1.x, accv[j][4]);
                    accv[j][5] = fmaf(av, v1.y, accv[j][5]);
                    accv[j][6] = fmaf(av, v1.z, accv[j][6]);
                    accv[j][7] = fmaf(av, v1.w, accv[j][7]);
                }
            }
        }
        __syncthreads();
        if (c < 3)      { fst_up(); ffld_up(c + 2 <= 3 ? c + 2 : 3); if (c == 2) ffld_dn(0); }
        else            { /* after last up chunk: act next */ }
        if (c < 3) __syncthreads();
    }

    // ---- act = gelu(gate)*val -> xs (xn dead) ----
    #pragma unroll
    for (int j = 0; j < 4; ++j) {
        int t = ti * 4 + j;
        float av[8];
        #pragma unroll
        for (int cc = 0; cc < 8; ++cc) {
            float g = accg[j][cc];
            av[cc] = 0.5f * g * (1.0f + erff(g * 0.70710678118654752f)) * accv[j][cc];
        }
        *(float4*)&xs[t * XS_STRIDE + o0]     = *(float4*)&av[0];
        *(float4*)&xs[t * XS_STRIDE + o0 + 4] = *(float4*)&av[4];
    }
    fst_dn();
    ffld_dn(1);
    __syncthreads();

    float accd[4][8];
    #pragma unroll
    for (int j = 0; j < 4; ++j)
        #pragma unroll
        for (int cc = 0; cc < 8; ++cc) accd[j][cc] = 0.f;

    // ---- DOWN: 4 chunks of 32 k ----
    for (int c = 0; c < 4; ++c) {
        const float* xsp = xs + (ti * 4) * XS_STRIDE + c * 32;
        #pragma unroll
        for (int k4 = 0; k4 < 8; ++k4) {
            float4 a[4];
            #pragma unroll
            for (int j = 0; j < 4; ++j)
                a[j] = *(const float4*)&xsp[j * XS_STRIDE + k4 * 4];
            #pragma unroll
            for (int i = 0; i < 4; ++i) {
                const float* wr = wt + (k4 * 4 + i) * 128;
                float4 b0 = *(const float4*)&wr[og];
                float4 b1 = *(const float4*)&wr[og + 4];
                #pragma unroll
                for (int j = 0; j < 4; ++j) {
                    float av = ((const float*)&a[j])[i];
                    accd[j][0] = fmaf(av, b0.x, accd[j][0]);
                    accd[j][1] = fmaf(av, b0.y, accd[j][1]);
                    accd[j][2] = fmaf(av, b0.z, accd[j][2]);
                    accd[j][3] = fmaf(av, b0.w, accd[j][3]);
                    accd[j][4] = fmaf(av, b1.x, accd[j][4]);
                    accd[j][5] = fmaf(av, b1.y, accd[j][5]);
                    accd[j][6] = fmaf(av, b1.z, accd[j][6]);
                    accd[j][7] = fmaf(av, b1.w, accd[j][7]);
                }
            }
        }
        __syncthreads();
        if (c < 3) { fst_dn(); ffld_dn(c + 2 <= 3 ? c + 2 : 3); __syncthreads(); }
    }

    // ---- epilogue: residual, write h (LAST=0), stash hnew in xs ----
    #pragma unroll
    for (int j = 0; j < 4; ++j) {
        int t = ti * 4 + j;
        size_t tok = tok0 + t;
        float4 h0 = *(const float4*)(h + tok * D + o0);
        float4 h1 = *(const float4*)(h + tok * D + o0 + 4);
        float4 n0, n1;
        n0.x = h0.x + accd[j][0]; n0.y = h0.y + accd[j][1];
        n0.z = h0.z + accd[j][2]; n0.w = h0.w + accd[j][3];
        n1.x = h1.x + accd[j][4]; n1.y = h1.y + accd[j][5];
        n1.z = h1.z + accd[j][6]; n1.w = h1.w + accd[j][7];
        if (!LAST) {
            *(float4*)(h + tok * D + o0)     = n0;
            *(float4*)(h + tok * D + o0 + 4) = n1;
        }
        *(float4*)&xs[t * XS_STRIDE + o0]     = n0;
        *(float4*)&xs[t * XS_STRIDE + o0 + 4] = n1;
    }
    __syncthreads();

    // ---- per-token tail (16 tokens per wave) ----
    if (!LAST) {
        for (int i = 0; i < 16; ++i) {
            int t = wv * 16 + i;
            float v1 = xs[t * XS_STRIDE + lane];
            float v2 = xs[t * XS_STRIDE + 64 + lane];
            float s1 = wsum64(v1 + v2);
            float s2 = wsum64(v1 * v1 + v2 * v2);
            float mu = s1 * (1.0f / D);
            float rs = rsqrtf(s2 * (1.0f / D) - mu * mu + EPS);
            if (lane == 0) {
                stats_out[(tok0 + t) * 2]     = mu;
                stats_out[(tok0 + t) * 2 + 1] = rs;
            }
        }
    } else {
        float pw1[VOCAB], pw2[VOCAB], pb[VOCAB];
        #pragma unroll
        for (int v = 0; v < VOCAB; ++v) {
            pw1[v] = projw[v * D + lane];
            pw2[v] = projw[v * D + 64 + lane];
            pb[v]  = projb[v];
        }
        for (int i = 0; i < 16; ++i) {
            int t = wv * 16 + i;
            float v1 = xs[t * XS_STRIDE + lane];
            float v2 = xs[t * XS_STRIDE + 64 + lane];
            float s1 = wsum64(v1 + v2);
            float s2 = wsum64(v1 * v1 + v2 * v2);
            float mu = s1 * (1.0f / D);
            float rs = rsqrtf(s2 * (1.0f / D) - mu * mu + EPS);
            float x1 = (v1 - mu) * rs * lastw[lane];
            float x2 = (v2 - mu) * rs * lastw[64 + lane];
            #pragma unroll
            for (int v = 0; v < VOCAB; ++v) {
                float pp = wsum64(fmaf(x1, pw1[v], x2 * pw2[v]));
                if (lane == 0) out[(tok0 + t) * VOCAB + v] = pp + pb[v];
            }
        }
    }
}

// ---------------------------------------------------------------------------
extern "C" void kernel_launch(void* const* d_in, const int* in_sizes, int n_in,
                              void* d_out, int out_size, void* d_ws, size_t ws_size,
                              hipStream_t stream)
{
    const int*   x     = (const int*)  d_in[0];
    const float* emb   = (const float*)d_in[1];
    const float* ln1   = (const float*)d_in[2];
    const float* Wg    = (const float*)d_in[3];
    const float* Rm    = (const float*)d_in[4];
    const float* bias  = (const float*)d_in[5];
    const float* gnw   = (const float*)d_in[6];
    const float* ln2   = (const float*)d_in[7];
    const float* wup   = (const float*)d_in[8];
    const float* wdn   = (const float*)d_in[9];
    const float* postw = (const float*)d_in[10];
    const float* projw = (const float*)d_in[11];
    const float* projb = (const float*)d_in[12];
    float* out   = (float*)d_out;
    float* hbuf  = (float*)d_ws;
    float* stats = hbuf + (size_t)NTOK * D;
    float* gxbuf = stats + (size_t)NTOK * 2;

    k_embed<<<NTOK / 4, 256, 0, stream>>>(x, emb, hbuf, stats);

    for (int bi = 0; bi < NB; ++bi) {
        k_gx<<<NTOK / 32, 256, 0, stream>>>(Wg + bi * 4 * NH * DH * DH,
                                            bias + bi * NH * 4 * DH,
                                            ln1 + bi * D,
                                            hbuf, stats, gxbuf);
        k_scan<<<B_SZ * NH, 64, 0, stream>>>(Rm + bi * NH * DH * 4 * DH,
                                             gnw + bi * D,
                                             gxbuf, hbuf);
        if (bi == 0)
            k_ff<0><<<NTOK / 64, 256, 0, stream>>>(hbuf, ln2 + bi * D,
                                                   wup + bi * 2 * D * D,
                                                   wdn + bi * D * D,
                                                   stats, nullptr, nullptr,
                                                   nullptr, nullptr);
        else
            k_ff<1><<<NTOK / 64, 256, 0, stream>>>(hbuf, ln2 + bi * D,
                                                   wup + bi * 2 * D * D,
                                                   wdn + bi * D * D,
                                                   nullptr, postw, projw,
                                                   projb, out);
    }
}

// Round 12
// 397.774 us; speedup vs baseline: 2.1243x; 2.1243x over previous
//
#include <hip/hip_runtime.h>
#include <math.h>

#define D      128
#define S_LEN  64
#define B_SZ   512
#define NH     4
#define DH     32
#define NB     2
#define VOCAB  9
#define EPS    1e-5f
#define NTOK   (B_SZ * S_LEN)

// ---------------- DPP helpers (ctrl must be compile-time constant) ----------
template <int CTRL>
__device__ __forceinline__ float dppf(float x) {
    return __int_as_float(__builtin_amdgcn_update_dpp(
        0, __float_as_int(x), CTRL, 0xF, 0xF, true));
}
__device__ __forceinline__ float wsum64(float x) {
    x += dppf<0x111>(x);
    x += dppf<0x112>(x);
    x += dppf<0x114>(x);
    x += dppf<0x118>(x);
    x += dppf<0x142>(x);
    x += dppf<0x143>(x);
    return __int_as_float(__builtin_amdgcn_readlane(__float_as_int(x), 63));
}

// LDS swizzles (all xor bits>=2 -> float4 alignment preserved)
__device__ __forceinline__ int xc3(int t, int c) { return c ^ (((t >> 1) & 7) << 2); }
__device__ __forceinline__ int xa (int t, int c) { return c ^ ((t & 7) << 2); }
__device__ __forceinline__ int xg (int c)        { return c ^ ((c >> 5) << 3); }

// ---------------------------------------------------------------------------
// Kernel 1: h = emb[x]; LN1 stats. One wave per token.
// ---------------------------------------------------------------------------
__global__ __launch_bounds__(256) void k_embed(const int* __restrict__ x,
                                               const float* __restrict__ emb,
                                               float* __restrict__ h,
                                               float* __restrict__ stats)
{
    int lane = threadIdx.x & 63;
    int wv   = threadIdx.x >> 6;
    int tok  = blockIdx.x * 4 + wv;
    int xi   = x[tok];
    float2 v = ((const float2*)(emb + xi * D))[lane];
    ((float2*)(h + (size_t)tok * D))[lane] = v;
    float s1 = wsum64(v.x + v.y);
    float s2 = wsum64(v.x * v.x + v.y * v.y);
    float mu  = s1 * (1.0f / D);
    float var = s2 * (1.0f / D) - mu * mu;
    if (lane == 0) {
        stats[tok * 2]     = mu;
        stats[tok * 2 + 1] = rsqrtf(var + EPS);
    }
}

// ---------------------------------------------------------------------------
// Kernel 1.5: gx = LN1(h) @ Wg + bias (R10 version, unchanged).
// ---------------------------------------------------------------------------
__global__ __launch_bounds__(256, 2) void k_gx(const float* __restrict__ Wg,
                                               const float* __restrict__ bias,
                                               const float* __restrict__ lnw,
                                               const float* __restrict__ h,
                                               const float* __restrict__ stats,
                                               float* __restrict__ gx)
{
    __shared__ float xs[32 * 128];
    __shared__ float wl[4 * 32 * 128];

    int tid  = threadIdx.x;
    int lane = tid & 63;
    int wv   = tid >> 6;
    size_t tok0 = (size_t)blockIdx.x * 32;

    {
        int q = tid & 7;
        #pragma unroll
        for (int it = 0; it < 16; ++it) {
            int row = it * 32 + (tid >> 3);
            int g  = row >> 7;
            int n  = (row >> 5) & 3;
            int hh = row & 31;
            float4 v = *(const float4*)(Wg + row * 32 + q * 4);
            int col = g * 32 + hh;
            int sw  = q << 2;
            float* dst = wl + n * 4096;
            dst[(q * 4 + 0) * 128 + (col ^ sw)] = v.x;
            dst[(q * 4 + 1) * 128 + (col ^ sw)] = v.y;
            dst[(q * 4 + 2) * 128 + (col ^ sw)] = v.z;
            dst[(q * 4 + 3) * 128 + (col ^ sw)] = v.w;
        }
    }
    for (int i = 0; i < 8; ++i) {
        int t = wv * 8 + i;
        const float* hp = h + (tok0 + t) * D;
        float mu = stats[(tok0 + t) * 2];
        float rs = stats[(tok0 + t) * 2 + 1];
        float v1 = (hp[lane]      - mu) * rs * lnw[lane];
        float v2 = (hp[64 + lane] - mu) * rs * lnw[64 + lane];
        xs[t * 128 + xg(lane)]      = v1;
        xs[t * 128 + xg(lane + 64)] = v2;
    }
    __syncthreads();

    int nh   = lane >> 4;
    int col0 = (lane & 15) * 8;
    int t0   = wv * 8;

    float acc[8][8];
    #pragma unroll
    for (int j = 0; j < 8; ++j)
        #pragma unroll
        for (int cc = 0; cc < 8; ++cc) acc[j][cc] = 0.f;

    const float* wbase = wl + nh * 4096;
    #pragma unroll
    for (int k4 = 0; k4 < 8; ++k4) {
        int sw  = k4 << 2;
        int ac4 = (nh * 32 + k4 * 4) ^ (nh << 3);
        float4 w0[4], w1[4];
        #pragma unroll
        for (int i = 0; i < 4; ++i) {
            int k = k4 * 4 + i;
            w0[i] = *(const float4*)&wbase[k * 128 + (col0 ^ sw)];
            w1[i] = *(const float4*)&wbase[k * 128 + ((col0 + 4) ^ sw)];
        }
        #pragma unroll
        for (int j = 0; j < 8; ++j) {
            float4 a4 = *(const float4*)&xs[(t0 + j) * 128 + ac4];
            #pragma unroll
            for (int i = 0; i < 4; ++i) {
                float a = ((const float*)&a4)[i];
                acc[j][0] = fmaf(a, w0[i].x, acc[j][0]);
                acc[j][1] = fmaf(a, w0[i].y, acc[j][1]);
                acc[j][2] = fmaf(a, w0[i].z, acc[j][2]);
                acc[j][3] = fmaf(a, w0[i].w, acc[j][3]);
                acc[j][4] = fmaf(a, w1[i].x, acc[j][4]);
                acc[j][5] = fmaf(a, w1[i].y, acc[j][5]);
                acc[j][6] = fmaf(a, w1[i].z, acc[j][6]);
                acc[j][7] = fmaf(a, w1[i].w, acc[j][7]);
            }
        }
    }

    float4 bb0 = *(const float4*)(bias + nh * 128 + col0);
    float4 bb1 = *(const float4*)(bias + nh * 128 + col0 + 4);
    #pragma unroll
    for (int j = 0; j < 8; ++j) {
        int gt = (int)tok0 + t0 + j;
        int bb = gt >> 6;
        int ss = gt & 63;
        float* op = gx + ((size_t)(bb * NH + nh) * S_LEN + ss) * 128 + col0;
        float4 o0v, o1v;
        o0v.x = acc[j][0] + bb0.x; o0v.y = acc[j][1] + bb0.y;
        o0v.z = acc[j][2] + bb0.z; o0v.w = acc[j][3] + bb0.w;
        o1v.x = acc[j][4] + bb1.x; o1v.y = acc[j][5] + bb1.y;
        o1v.z = acc[j][6] + bb1.z; o1v.w = acc[j][7] + bb1.w;
        *(float4*)op       = o0v;
        *(float4*)(op + 4) = o1v;
    }
}

// ---------------------------------------------------------------------------
// Kernel 2 (rewritten): one block (256 thr = 4 waves = 4 heads) per batch b.
// The 64 steps are processed in 4 chunks of 16; each chunk's gx slab (own
// head, contiguous) and h rows are bulk-staged into LDS (coalesced float4),
// double-buffered -> per-step loads are conflict-free ds_reads, global
// latency paid once per ~4800-cyc chunk. R goes global->LDS->VGPR (ds_read
// source cannot be rematerialized). LDS 80 KB -> 2 blocks/CU.
// ---------------------------------------------------------------------------
__global__ __launch_bounds__(256, 1) void k_scan(const float* __restrict__ Rm,   // (NH,DH,128)
                                                 const float* __restrict__ gnw,  // (D)
                                                 const float* __restrict__ gx,   // (B*NH*S,128)
                                                 float* __restrict__ h)          // (B*S,D) in/out
{
    __shared__ float lds[20480];   // [0,16384): R stage, then gx dbuf (2x8192)
                                   // [16384,20480): h dbuf (2x2048)

    int tid  = threadIdx.x;
    int n    = tid >> 6;           // head = wave index
    int lane = tid & 63;
    int e    = lane >> 1;
    int sub  = lane & 1;
    int colA = sub * DH + e;       // i (sub0) / f (sub1); +64 -> z/o
    int b    = blockIdx.x;

    // ---- phase 0: stage all R (16384 floats) into LDS, coalesced ----
    {
        const float4* src = (const float4*)Rm;
        #pragma unroll
        for (int it = 0; it < 16; ++it) {
            int f4 = it * 256 + tid;
            *(float4*)&lds[f4 * 4] = src[f4];
        }
    }
    __syncthreads();
    // each lane pulls its 64 weights into VGPRs (bank = e -> 2-way, free)
    float RA[DH], RB[DH];
    #pragma unroll
    for (int i = 0; i < DH; ++i) {
        RA[i] = lds[(n * DH + i) * 128 + colA];
        RB[i] = lds[(n * DH + i) * 128 + 64 + colA];
    }
    float gw = gnw[n * DH + e];
    __syncthreads();               // R region now free for gx staging

    const float* gxp = gx + ((size_t)(b * NH + n) * S_LEN) * 128;  // head slab
    const float* hbr = h + (size_t)b * S_LEN * D;                  // h rows (read)
    float*       hbw = h + (size_t)b * S_LEN * D + n * DH;         // h write base

    float4 gxr[8], hr2[2];
    auto ld_chunk = [&](int c) {
        const float* p = gxp + c * 2048;          // 16 rows x 128, contiguous
        #pragma unroll
        for (int k = 0; k < 8; ++k)
            gxr[k] = *(const float4*)(p + (k * 64 + lane) * 4);
        const float* q = hbr + c * 2048;
        #pragma unroll
        for (int k = 0; k < 2; ++k)
            hr2[k] = *(const float4*)(q + (k * 256 + tid) * 4);
    };
    auto st_chunk = [&](int buf) {
        float* g = lds + buf * 8192 + n * 2048;   // own-head region
        #pragma unroll
        for (int k = 0; k < 8; ++k)
            *(float4*)&g[(k * 64 + lane) * 4] = gxr[k];
        float* hh = lds + 16384 + buf * 2048;     // shared h region
        #pragma unroll
        for (int k = 0; k < 2; ++k)
            *(float4*)&hh[(k * 256 + tid) * 4] = hr2[k];
    };

    ld_chunk(0); st_chunk(0); ld_chunk(1);
    __syncthreads();               // buf0 ready (h is cross-wave)

    float c_ = 0.f, nacc = 0.f, m = 0.f;
    float hu[DH];
    #pragma unroll
    for (int i = 0; i < DH; ++i) hu[i] = 0.f;

    for (int c = 0; c < 4; ++c) {
        int buf = c & 1;
        const float* g  = lds + buf * 8192 + n * 2048;
        const float* hh = lds + 16384 + buf * 2048;

        for (int i = 0; i < 16; ++i) {
            float gA   = g[i * 128 + colA];
            float gB   = g[i * 128 + 64 + colA];
            float hres = hh[i * 128 + n * 32 + e];

            float r0=0,r1=0,r2=0,r3=0,q0=0,q1=0,q2=0,q3=0;
            #pragma unroll
            for (int k = 0; k < DH; k += 4) {
                r0 = fmaf(hu[k],   RA[k],   r0);
                r1 = fmaf(hu[k+1], RA[k+1], r1);
                r2 = fmaf(hu[k+2], RA[k+2], r2);
                r3 = fmaf(hu[k+3], RA[k+3], r3);
                q0 = fmaf(hu[k],   RB[k],   q0);
                q1 = fmaf(hu[k+1], RB[k+1], q1);
                q2 = fmaf(hu[k+2], RB[k+2], q2);
                q3 = fmaf(hu[k+3], RB[k+3], q3);
            }
            float rawA = gA + ((r0 + r1) + (r2 + r3));
            float rawB = gB + ((q0 + q1) + (q2 + q3));

            float xA = dppf<0xB1>(rawA);   // quad_perm xor1
            float xB = dppf<0xB1>(rawB);
            float i_r = sub ? xA   : rawA;
            float f_r = sub ? rawA : xA;
            float z_r = sub ? xB   : rawB;
            float o_r = sub ? rawB : xB;

            float lsf  = fminf(f_r, 0.f)
                       - 0.69314718055994531f * __log2f(1.0f + __expf(-fabsf(f_r)));
            float lfm  = m + lsf;
            float mnew = fmaxf(i_r, lfm);
            float ig   = __expf(i_r - mnew);
            float fg   = __expf(lfm - mnew);
            float t    = __expf(2.f * z_r);
            float tz   = 1.f - 2.f / (t + 1.f);
            c_   = fg * c_ + ig * tz;
            nacc = fg * nacc + ig;
            m    = mnew;
            float hv = c_ / (nacc * (1.f + __expf(-o_r)));

            float s1 = wsum64(hv);
            float s2 = wsum64(hv * hv);
            float mu  = s1 * (1.f / 64.f);
            float var = s2 * (1.f / 64.f) - mu * mu;
            float hn  = (hv - mu) * rsqrtf(var + EPS) * gw;

            if (!sub) hbw[(c * 16 + i) * D + e] = hres + hn;

            #pragma unroll
            for (int k = 0; k < DH; ++k)
                hu[k] = __int_as_float(
                    __builtin_amdgcn_readlane(__float_as_int(hv), 2 * k));
        }

        if (c < 3) {
            st_chunk((c + 1) & 1);     // other buffer: no reader conflict
            if (c < 2) ld_chunk(c + 2);
            __syncthreads();
        }
    }
}

// ---------------------------------------------------------------------------
// Kernel 3: fused LN2 -> up GEMM -> GeLU -> down GEMM -> residual -> tail.
// Reverted to the proven R10 version (70 us, VGPR 80, zero spill).
// ---------------------------------------------------------------------------
template <int LAST>
__global__ __launch_bounds__(256, 3) void k_ff(float* __restrict__ h,
                                               const float* __restrict__ ln2w,
                                               const float* __restrict__ wup,    // (2D, D)
                                               const float* __restrict__ wdn,    // (D, D)
                                               float* __restrict__ stats_out,
                                               const float* __restrict__ lastw,
                                               const float* __restrict__ projw,
                                               const float* __restrict__ projb,
                                               float* __restrict__ out)
{
    __shared__ float xs[32 * 128];      // 16 KiB
    __shared__ float as_[32 * 64];      // 8 KiB
    __shared__ float wt[2 * 32 * 64];   // 16 KiB

    int tid  = threadIdx.x;
    int lane = tid & 63;
    int wv   = tid >> 6;
    size_t tok0 = (size_t)blockIdx.x * 32;

    for (int i = 0; i < 8; ++i) {
        int t = wv * 8 + i;
        const float* hp = h + (tok0 + t) * D;
        float v1 = hp[lane], v2 = hp[64 + lane];
        float s1 = wsum64(v1 + v2);
        float s2 = wsum64(v1 * v1 + v2 * v2);
        float mu = s1 * (1.0f / D);
        float rs = rsqrtf(s2 * (1.0f / D) - mu * mu + EPS);
        xs[t * D + xc3(t, lane)]      = (v1 - mu) * rs * ln2w[lane];
        xs[t * D + xc3(t, lane + 64)] = (v2 - mu) * rs * ln2w[64 + lane];
    }

    int q     = tid & 7;
    int r0    = tid >> 3;
    int goff0 = r0 * D + q * 4;
    int goff1 = (r0 + 32) * D + q * 4;
    int s0    = r0 ^ (q << 2);
    int kb    = q * 4;

    auto ffld = [&](int id, float4* pre) {
        int p = (id >= 6) ? 1 : 0;
        int j = id - p * 6;
        const float* b0;
        const float* b1;
        if (j < 4) { b0 = wup + (p * 64) * D + j * 32;
                     b1 = wup + (128 + p * 64) * D + j * 32; }
        else       { int jj = j - 4;
                     b0 = wdn + p * 64 + jj * 32;
                     b1 = wdn + 64 * D + p * 64 + jj * 32; }
        pre[0] = *(const float4*)(b0 + goff0);
        pre[1] = *(const float4*)(b0 + goff1);
        pre[2] = *(const float4*)(b1 + goff0);
        pre[3] = *(const float4*)(b1 + goff1);
    };
    auto fst = [&](const float4* pre) {
        #pragma unroll
        for (int cc = 0; cc < 4; ++cc) {
            const float* p0 = (const float*)&pre[0];
            const float* p1 = (const float*)&pre[1];
            const float* p2 = (const float*)&pre[2];
            const float* p3 = (const float*)&pre[3];
            wt[(kb + cc) * 64 + s0]           = p0[cc];
            wt[(kb + cc) * 64 + s0 + 32]      = p1[cc];
            wt[2048 + (kb + cc) * 64 + s0]      = p2[cc];
            wt[2048 + (kb + cc) * 64 + s0 + 32] = p3[cc];
        }
    };

    int ti = tid >> 4;
    int oi = tid & 15;
    int t0 = ti * 2;
    int o0 = oi * 4;

    float accd[2][2][4];
    #pragma unroll
    for (int a1 = 0; a1 < 2; ++a1)
        #pragma unroll
        for (int j = 0; j < 2; ++j)
            #pragma unroll
            for (int cc = 0; cc < 4; ++cc) accd[a1][j][cc] = 0.f;

    float4 pre[4];
    ffld(0, pre);
    int id = 1;

    #pragma unroll
    for (int p = 0; p < 2; ++p) {
        float accg[2][4], accv[2][4];
        #pragma unroll
        for (int j = 0; j < 2; ++j)
            #pragma unroll
            for (int cc = 0; cc < 4; ++cc) { accg[j][cc] = 0.f; accv[j][cc] = 0.f; }

        for (int c4 = 0; c4 < 4; ++c4) {
            __syncthreads();
            fst(pre);
            if (id < 12) ffld(id, pre);
            ++id;
            __syncthreads();
            int kc = c4 * 32;
            #pragma unroll
            for (int k4 = 0; k4 < 8; ++k4) {
                float4 a0 = *(const float4*)&xs[t0 * D + xc3(t0, kc + k4 * 4)];
                float4 a1v = *(const float4*)&xs[(t0 + 1) * D + xc3(t0 + 1, kc + k4 * 4)];
                int ws = k4 << 2;
                #pragma unroll
                for (int i = 0; i < 4; ++i) {
                    int k = k4 * 4 + i;
                    float4 bg = *(const float4*)&wt[k * 64 + (o0 ^ ws)];
                    float4 bv = *(const float4*)&wt[2048 + k * 64 + (o0 ^ ws)];
                    float ax0 = ((const float*)&a0)[i];
                    float ax1 = ((const float*)&a1v)[i];
                    accg[0][0] = fmaf(ax0, bg.x, accg[0][0]);
                    accg[0][1] = fmaf(ax0, bg.y, accg[0][1]);
                    accg[0][2] = fmaf(ax0, bg.z, accg[0][2]);
                    accg[0][3] = fmaf(ax0, bg.w, accg[0][3]);
                    accg[1][0] = fmaf(ax1, bg.x, accg[1][0]);
                    accg[1][1] = fmaf(ax1, bg.y, accg[1][1]);
                    accg[1][2] = fmaf(ax1, bg.z, accg[1][2]);
                    accg[1][3] = fmaf(ax1, bg.w, accg[1][3]);
                    accv[0][0] = fmaf(ax0, bv.x, accv[0][0]);
                    accv[0][1] = fmaf(ax0, bv.y, accv[0][1]);
                    accv[0][2] = fmaf(ax0, bv.z, accv[0][2]);
                    accv[0][3] = fmaf(ax0, bv.w, accv[0][3]);
                    accv[1][0] = fmaf(ax1, bv.x, accv[1][0]);
                    accv[1][1] = fmaf(ax1, bv.y, accv[1][1]);
                    accv[1][2] = fmaf(ax1, bv.z, accv[1][2]);
                    accv[1][3] = fmaf(ax1, bv.w, accv[1][3]);
                }
            }
        }
        #pragma unroll
        for (int j = 0; j < 2; ++j) {
            int t = t0 + j;
            float4 av;
            float* ap = (float*)&av;
            #pragma unroll
            for (int cc = 0; cc < 4; ++cc) {
                float g = accg[j][cc];
                float u = accv[j][cc];
                ap[cc] = 0.5f * g * (1.0f + erff(g * 0.70710678118654752f)) * u;
            }
            *(float4*)&as_[t * 64 + xa(t, o0)] = av;
        }
        for (int c2 = 0; c2 < 2; ++c2) {
            __syncthreads();
            fst(pre);
            if (id < 12) ffld(id, pre);
            ++id;
            __syncthreads();
            int kc = c2 * 32;
            #pragma unroll
            for (int k4 = 0; k4 < 8; ++k4) {
                float4 a0 = *(const float4*)&as_[t0 * 64 + xa(t0, kc + k4 * 4)];
                float4 a1v = *(const float4*)&as_[(t0 + 1) * 64 + xa(t0 + 1, kc + k4 * 4)];
                int ws = k4 << 2;
                #pragma unroll
                for (int i = 0; i < 4; ++i) {
                    int k = k4 * 4 + i;
                    float4 b0v = *(const float4*)&wt[k * 64 + (o0 ^ ws)];
                    float4 b1v = *(const float4*)&wt[2048 + k * 64 + (o0 ^ ws)];
                    float ax0 = ((const float*)&a0)[i];
                    float ax1 = ((const float*)&a1v)[i];
                    accd[0][0][0] = fmaf(ax0, b0v.x, accd[0][0][0]);
                    accd[0][0][1] = fmaf(ax0, b0v.y, accd[0][0][1]);
                    accd[0][0][2] = fmaf(ax0, b0v.z, accd[0][0][2]);
                    accd[0][0][3] = fmaf(ax0, b0v.w, accd[0][0][3]);
                    accd[0][1][0] = fmaf(ax1, b0v.x, accd[0][1][0]);
                    accd[0][1][1] = fmaf(ax1, b0v.y, accd[0][1][1]);
                    accd[0][1][2] = fmaf(ax1, b0v.z, accd[0][1][2]);
                    accd[0][1][3] = fmaf(ax1, b0v.w, accd[0][1][3]);
                    accd[1][0][0] = fmaf(ax0, b1v.x, accd[1][0][0]);
                    accd[1][0][1] = fmaf(ax0, b1v.y, accd[1][0][1]);
                    accd[1][0][2] = fmaf(ax0, b1v.z, accd[1][0][2]);
                    accd[1][0][3] = fmaf(ax0, b1v.w, accd[1][0][3]);
                    accd[1][1][0] = fmaf(ax1, b1v.x, accd[1][1][0]);
                    accd[1][1][1] = fmaf(ax1, b1v.y, accd[1][1][1]);
                    accd[1][1][2] = fmaf(ax1, b1v.z, accd[1][1][2]);
                    accd[1][1][3] = fmaf(ax1, b1v.w, accd[1][1][3]);
                }
            }
        }
    }

    #pragma unroll
    for (int j = 0; j < 2; ++j) {
        int t = t0 + j;
        size_t tok = tok0 + t;
        #pragma unroll
        for (int a1 = 0; a1 < 2; ++a1) {
            int cb = a1 * 64 + o0;
            float4 hres = *(const float4*)(h + tok * D + cb);
            float4 hn;
            hn.x = hres.x + accd[a1][j][0];
            hn.y = hres.y + accd[a1][j][1];
            hn.z = hres.z + accd[a1][j][2];
            hn.w = hres.w + accd[a1][j][3];
            if (!LAST) *(float4*)(h + tok * D + cb) = hn;
            *(float4*)&xs[t * D + xc3(t, cb)] = hn;
        }
    }
    __syncthreads();

    if (!LAST) {
        for (int i = 0; i < 8; ++i) {
            int t = wv * 8 + i;
            float v1 = xs[t * D + xc3(t, lane)];
            float v2 = xs[t * D + xc3(t, lane + 64)];
            float s1 = wsum64(v1 + v2);
            float s2 = wsum64(v1 * v1 + v2 * v2);
            float mu = s1 * (1.0f / D);
            float rs = rsqrtf(s2 * (1.0f / D) - mu * mu + EPS);
            if (lane == 0) {
                stats_out[(tok0 + t) * 2]     = mu;
                stats_out[(tok0 + t) * 2 + 1] = rs;
            }
        }
    } else {
        float pw1[VOCAB], pw2[VOCAB], pb[VOCAB];
        #pragma unroll
        for (int v = 0; v < VOCAB; ++v) {
            pw1[v] = projw[v * D + lane];
            pw2[v] = projw[v * D + 64 + lane];
            pb[v]  = projb[v];
        }
        for (int i = 0; i < 8; ++i) {
            int t = wv * 8 + i;
            float v1 = xs[t * D + xc3(t, lane)];
            float v2 = xs[t * D + xc3(t, lane + 64)];
            float s1 = wsum64(v1 + v2);
            float s2 = wsum64(v1 * v1 + v2 * v2);
            float mu = s1 * (1.0f / D);
            float rs = rsqrtf(s2 * (1.0f / D) - mu * mu + EPS);
            float x1 = (v1 - mu) * rs * lastw[lane];
            float x2 = (v2 - mu) * rs * lastw[64 + lane];
            #pragma unroll
            for (int v = 0; v < VOCAB; ++v) {
                float pp = wsum64(fmaf(x1, pw1[v], x2 * pw2[v]));
                if (lane == 0) out[(tok0 + t) * VOCAB + v] = pp + pb[v];
            }
        }
    }
}

// ---------------------------------------------------------------------------
extern "C" void kernel_launch(void* const* d_in, const int* in_sizes, int n_in,
                              void* d_out, int out_size, void* d_ws, size_t ws_size,
                              hipStream_t stream)
{
    const int*   x     = (const int*)  d_in[0];
    const float* emb   = (const float*)d_in[1];
    const float* ln1   = (const float*)d_in[2];
    const float* Wg    = (const float*)d_in[3];
    const float* Rm    = (const float*)d_in[4];
    const float* bias  = (const float*)d_in[5];
    const float* gnw   = (const float*)d_in[6];
    const float* ln2   = (const float*)d_in[7];
    const float* wup   = (const float*)d_in[8];
    const float* wdn   = (const float*)d_in[9];
    const float* postw = (const float*)d_in[10];
    const float* projw = (const float*)d_in[11];
    const float* projb = (const float*)d_in[12];
    float* out   = (float*)d_out;
    float* hbuf  = (float*)d_ws;
    float* stats = hbuf + (size_t)NTOK * D;
    float* gxbuf = stats + (size_t)NTOK * 2;

    k_embed<<<NTOK / 4, 256, 0, stream>>>(x, emb, hbuf, stats);

    for (int bi = 0; bi < NB; ++bi) {
        k_gx<<<NTOK / 32, 256, 0, stream>>>(Wg + bi * 4 * NH * DH * DH,
                                            bias + bi * NH * 4 * DH,
                                            ln1 + bi * D,
                                            hbuf, stats, gxbuf);
        k_scan<<<B_SZ, 256, 0, stream>>>(Rm + bi * NH * DH * 4 * DH,
                                         gnw + bi * D,
                                         gxbuf, hbuf);
        if (bi == 0)
            k_ff<0><<<NTOK / 32, 256, 0, stream>>>(hbuf, ln2 + bi * D,
                                                   wup + bi * 2 * D * D,
                                                   wdn + bi * D * D,
                                                   stats, nullptr, nullptr,
                                                   nullptr, nullptr);
        else
            k_ff<1><<<NTOK / 32, 256, 0, stream>>>(hbuf, ln2 + bi * D,
                                                   wup + bi * 2 * D * D,
                                                   wdn + bi * D * D,
                                                   nullptr, postw, projw,
                                                   projb, out);
    }
}